// Round 1
// baseline (356.590 us; speedup 1.0000x reference)
//
#include <hip/hip_runtime.h>
#include <hip/hip_fp16.h>
#include <stdint.h>

// Atten_L: B=2, L=64, C=256, S=256, D=512. fp32 I/O, fp16 MFMA compute.
// R4: (a) QK^T + softmax + PV fused into ONE kernel: P lives in LDS
//     (swizzled [128][256]), V^T panel staged to LDS (64KB), normalization
//     deferred to O-write via per-row 1/sum. Saves P HBM round-trip (32MB)
//     and the K=256 PV launch entirely. ao overlays qh (block writes only
//     the rows it alone reads, after its last read of them).
// (b) q/k/v projections merged into one 3072-block launch (tail overlap,
//     2 fewer launch gaps). XCD-aware swizzle kept everywhere.

typedef _Float16 f16;
typedef __attribute__((ext_vector_type(8))) _Float16 f16x8;
typedef __attribute__((ext_vector_type(4))) _Float16 f16x4;
typedef __attribute__((ext_vector_type(4))) float f32x4;

#define BM 128
#define BN 128
#define BK 64

__device__ __forceinline__ void glds16(const void* g, void* l)
{
    __builtin_amdgcn_global_load_lds(
        (const __attribute__((address_space(1))) void*)(uintptr_t)g,
        (__attribute__((address_space(3))) void*)(uint32_t)(uintptr_t)l,
        16, 0, 0);
}

// ---------------- generic NT GEMM (kept for the output projection) --------
// C[z][m][n] = sum_k A[z][m][k] * Bt[z][n][k] (+ bias[n])
template<bool A_F32, bool OUT_F32, bool TRANS_OUT, bool BIAS, int SWZ>
__global__ __launch_bounds__(256)
void gemm_nt(const void* __restrict__ Ap, const f16* __restrict__ Btp,
             const float* __restrict__ bias, void* __restrict__ Cp,
             int N, int K, long sA, long sB, long sC)
{
    __shared__ f16 As[BM][BK];
    __shared__ f16 Bs[BN][BK];

    const int p    = blockIdx.x;
    const int xcd  = p & 7;
    const int slot = p >> 3;
    int z, m0, n0;
    if (SWZ == 1) {            // 256 m-tiles x 4 n-tiles
        z  = 0;
        m0 = (xcd + 8 * (slot >> 2)) * BM;
        n0 = (slot & 3) * BN;
    } else {                   // 128 z x 2 m x 4 n
        z  = xcd + 8 * (slot >> 3);
        const int inner = slot & 7;
        m0 = (inner >> 2) * BM;
        n0 = (inner & 3) * BN;
    }

    const int tid  = threadIdx.x;
    const int lane = tid & 63;
    const int wave = tid >> 6;
    const int quad = lane >> 4;
    const int l16  = lane & 15;
    const int wr   = wave >> 1;
    const int wc   = wave & 1;

    const float* Af = (const float*)Ap + (long)z * sA;
    const f16*   Ah = (const f16*)Ap + (long)z * sA;
    const f16*   Bt = Btp + (long)z * sB;

    f32x4 acc[4][4];
    #pragma unroll
    for (int i = 0; i < 4; ++i)
        #pragma unroll
        for (int j = 0; j < 4; ++j)
            acc[i][j] = (f32x4){0.f, 0.f, 0.f, 0.f};

    const int i8 = lane >> 3;
    const int cl = (((lane & 7) - i8) & 7) * 8;

    const int ar = tid >> 3;
    const int ac = (tid & 7) * 8;

    float4 pre[8];
    auto load_a_f32 = [&](int k0) {
        #pragma unroll
        for (int h = 0; h < 4; ++h) {
            const float* s = Af + (long)(m0 + h * 32 + ar) * K + k0 + ac;
            pre[2 * h]     = *(const float4*)s;
            pre[2 * h + 1] = *(const float4*)(s + 4);
        }
    };
    auto store_a = [&]() {
        #pragma unroll
        for (int h = 0; h < 4; ++h) {
            const int r  = h * 32 + ar;
            const int pc = (ac + ((r & 7) * 8)) & 63;
            f16x8 v;
            v[0] = (f16)pre[2*h].x;   v[1] = (f16)pre[2*h].y;
            v[2] = (f16)pre[2*h].z;   v[3] = (f16)pre[2*h].w;
            v[4] = (f16)pre[2*h+1].x; v[5] = (f16)pre[2*h+1].y;
            v[6] = (f16)pre[2*h+1].z; v[7] = (f16)pre[2*h+1].w;
            *(f16x8*)&As[r][pc] = v;
        }
    };

    for (int k0 = 0; k0 < K; k0 += BK) {
        if (A_F32) {
            if (k0 == 0) load_a_f32(0);
            if (k0) __syncthreads();
            #pragma unroll
            for (int j = 0; j < 4; ++j) {
                const int R0 = (wave * 4 + j) * 8;
                glds16(Bt + (long)(n0 + R0 + i8) * K + k0 + cl, &Bs[R0][0]);
            }
            store_a();
        } else {
            if (k0) __syncthreads();
            #pragma unroll
            for (int j = 0; j < 4; ++j) {
                const int R0 = (wave * 4 + j) * 8;
                glds16(Ah + (long)(m0 + R0 + i8) * K + k0 + cl, &As[R0][0]);
                glds16(Bt + (long)(n0 + R0 + i8) * K + k0 + cl, &Bs[R0][0]);
            }
        }
        __syncthreads();
        if (A_F32 && k0 + BK < K) load_a_f32(k0 + BK);

        #pragma unroll
        for (int ksub = 0; ksub < 2; ++ksub) {
            f16x8 af[4], bf[4];
            #pragma unroll
            for (int i = 0; i < 4; ++i) {
                const int r  = wr * 64 + i * 16 + l16;
                const int pc = ((ksub * 32 + quad * 8) + ((r & 7) * 8)) & 63;
                af[i] = *(const f16x8*)&As[r][pc];
            }
            #pragma unroll
            for (int j = 0; j < 4; ++j) {
                const int r  = wc * 64 + j * 16 + l16;
                const int pc = ((ksub * 32 + quad * 8) + ((r & 7) * 8)) & 63;
                bf[j] = *(const f16x8*)&Bs[r][pc];
            }
            #pragma unroll
            for (int i = 0; i < 4; ++i)
                #pragma unroll
                for (int j = 0; j < 4; ++j)
                    acc[i][j] = __builtin_amdgcn_mfma_f32_16x16x32_f16(
                        af[i], bf[j], acc[i][j], 0, 0, 0);
        }
    }

    #pragma unroll
    for (int i = 0; i < 4; ++i) {
        #pragma unroll
        for (int j = 0; j < 4; ++j) {
            const int col = n0 + wc * 64 + j * 16 + l16;
            const float bv = BIAS ? bias[col] : 0.0f;
            #pragma unroll
            for (int r = 0; r < 4; ++r) {
                const int row = m0 + wr * 64 + i * 16 + quad * 4 + r;
                const float val = acc[i][j][r] + bv;
                if (TRANS_OUT) {
                    ((f16*)Cp)[(long)(row >> 8) * 131072 + (long)col * 256 + (row & 255)] = (f16)val;
                } else if (OUT_F32) {
                    ((float*)Cp)[(long)z * sC + (long)row * N + col] = val;
                } else {
                    ((f16*)Cp)[(long)z * sC + (long)row * N + col] = (f16)val;
                }
            }
        }
    }
}

// ---------------- merged q/k/v projection: 3072 blocks ----------------
// which = blockIdx>>10 selects (queries->qh), (keys->kh), (values->vT^T).
__global__ __launch_bounds__(256)
void proj3(const float* __restrict__ qin, const float* __restrict__ kin,
           const float* __restrict__ vin, const f16* __restrict__ wq,
           const f16* __restrict__ wkv, const float* __restrict__ bq,
           const float* __restrict__ bkv, f16* __restrict__ qh,
           f16* __restrict__ kh, f16* __restrict__ vT)
{
    __shared__ f16 As[BM][BK];
    __shared__ f16 Bs[BN][BK];

    const int p     = blockIdx.x;
    const int which = p >> 10;
    const int inner = p & 1023;
    const int xcd   = inner & 7;
    const int slot  = inner >> 3;
    const int m0 = (xcd + 8 * (slot >> 2)) * BM;
    const int n0 = (slot & 3) * BN;

    const float* A    = (which == 0) ? qin : (which == 1) ? kin : vin;
    const f16*   Bt   = (which == 0) ? wq : wkv;
    const float* bias = (which == 0) ? bq : bkv;
    const bool   trans = (which == 2);

    const int tid  = threadIdx.x;
    const int lane = tid & 63;
    const int wave = tid >> 6;
    const int quad = lane >> 4;
    const int l16  = lane & 15;
    const int wr   = wave >> 1;
    const int wc   = wave & 1;

    f32x4 acc[4][4];
    #pragma unroll
    for (int i = 0; i < 4; ++i)
        #pragma unroll
        for (int j = 0; j < 4; ++j)
            acc[i][j] = (f32x4){0.f, 0.f, 0.f, 0.f};

    const int i8 = lane >> 3;
    const int cl = (((lane & 7) - i8) & 7) * 8;
    const int ar = tid >> 3;
    const int ac = (tid & 7) * 8;

    float4 pre[8];
    auto load_a_f32 = [&](int k0) {
        #pragma unroll
        for (int h = 0; h < 4; ++h) {
            const float* s = A + (long)(m0 + h * 32 + ar) * 512 + k0 + ac;
            pre[2 * h]     = *(const float4*)s;
            pre[2 * h + 1] = *(const float4*)(s + 4);
        }
    };
    auto store_a = [&]() {
        #pragma unroll
        for (int h = 0; h < 4; ++h) {
            const int r  = h * 32 + ar;
            const int pc = (ac + ((r & 7) * 8)) & 63;
            f16x8 v;
            v[0] = (f16)pre[2*h].x;   v[1] = (f16)pre[2*h].y;
            v[2] = (f16)pre[2*h].z;   v[3] = (f16)pre[2*h].w;
            v[4] = (f16)pre[2*h+1].x; v[5] = (f16)pre[2*h+1].y;
            v[6] = (f16)pre[2*h+1].z; v[7] = (f16)pre[2*h+1].w;
            *(f16x8*)&As[r][pc] = v;
        }
    };

    for (int k0 = 0; k0 < 512; k0 += BK) {
        if (k0 == 0) load_a_f32(0);
        if (k0) __syncthreads();
        #pragma unroll
        for (int j = 0; j < 4; ++j) {
            const int R0 = (wave * 4 + j) * 8;
            glds16(Bt + (long)(n0 + R0 + i8) * 512 + k0 + cl, &Bs[R0][0]);
        }
        store_a();
        __syncthreads();
        if (k0 + BK < 512) load_a_f32(k0 + BK);

        #pragma unroll
        for (int ksub = 0; ksub < 2; ++ksub) {
            f16x8 af[4], bf[4];
            #pragma unroll
            for (int i = 0; i < 4; ++i) {
                const int r  = wr * 64 + i * 16 + l16;
                const int pc = ((ksub * 32 + quad * 8) + ((r & 7) * 8)) & 63;
                af[i] = *(const f16x8*)&As[r][pc];
            }
            #pragma unroll
            for (int j = 0; j < 4; ++j) {
                const int r  = wc * 64 + j * 16 + l16;
                const int pc = ((ksub * 32 + quad * 8) + ((r & 7) * 8)) & 63;
                bf[j] = *(const f16x8*)&Bs[r][pc];
            }
            #pragma unroll
            for (int i = 0; i < 4; ++i)
                #pragma unroll
                for (int j = 0; j < 4; ++j)
                    acc[i][j] = __builtin_amdgcn_mfma_f32_16x16x32_f16(
                        af[i], bf[j], acc[i][j], 0, 0, 0);
        }
    }

    f16* qout = (which == 0) ? qh : kh;
    #pragma unroll
    for (int i = 0; i < 4; ++i) {
        #pragma unroll
        for (int j = 0; j < 4; ++j) {
            const int col = n0 + wc * 64 + j * 16 + l16;
            const float bv = bias[col];
            #pragma unroll
            for (int r = 0; r < 4; ++r) {
                const int row = m0 + wr * 64 + i * 16 + quad * 4 + r;
                const float val = acc[i][j][r] + bv;
                if (trans)
                    vT[(long)(row >> 8) * 131072 + (long)col * 256 + (row & 255)] = (f16)val;
                else
                    qout[(long)row * 512 + col] = (f16)val;
            }
        }
    }
}

// ---------------- fused QK^T + softmax + PV ----------------
// 256 blocks (one per (z, m-half)), 512 threads = 8 waves in 2x4.
// Stage 1: S = Q K^T (128x256) in regs, softmax in regs/LDS-red.
// P (unnormalized e<=1) -> LDS [128][256] with per-64-col rotation swizzle.
// Stage 2: O = P V (K=256 entirely from LDS), V^T panel staged 64KB/chunk.
// O scaled by per-row 1/sum at write. O overlays qh.
__global__ __launch_bounds__(512)
void attn_fused(const f16* __restrict__ q, const f16* __restrict__ k,
                const f16* __restrict__ vT, f16* __restrict__ O)
{
    __shared__ __align__(16) f16 bufA[128 * 256];   // 64KB: As+Bs, then Ps
    __shared__ __align__(16) f16 Vs[4][128][64];    // 64KB: V^T panel (kblk-major)
    __shared__ float red[2][128][4];                //  4KB

    f16 (*As)[BK]  = (f16(*)[BK])bufA;              // [128][64]
    f16 (*Bs)[BK]  = (f16(*)[BK])(bufA + 128 * 64); // [256][64]
    f16 (*Ps)[256] = (f16(*)[256])bufA;             // [128][256]

    const int p    = blockIdx.x;
    const int xcd  = p & 7;
    const int slot = p >> 3;
    const int z    = xcd + 8 * (slot >> 1);
    const int m0   = (slot & 1) * 128;

    const int tid  = threadIdx.x;
    const int lane = tid & 63;
    const int wave = tid >> 6;
    const int quad = lane >> 4;
    const int l16  = lane & 15;
    const int wr   = wave >> 2;        // 0..1 row half
    const int wc   = wave & 3;         // 0..3 col quarter

    const f16* Aq = q  + (long)z * 131072 + (long)m0 * 512;
    const f16* Bk = k  + (long)z * 131072;
    const f16* Vt = vT + (long)z * 131072;

    f32x4 acc[4][4];
    #pragma unroll
    for (int i = 0; i < 4; ++i)
        #pragma unroll
        for (int j = 0; j < 4; ++j)
            acc[i][j] = (f32x4){0.f, 0.f, 0.f, 0.f};

    const int i8 = lane >> 3;
    const int cl = (((lane & 7) - i8) & 7) * 8;

    // ---- stage 1: S = Q K^T ----
    for (int k0 = 0; k0 < 512; k0 += BK) {
        if (k0) __syncthreads();
        #pragma unroll
        for (int g = 0; g < 2; ++g) {
            const int R0 = (wave * 2 + g) * 8;
            glds16(Aq + (long)(R0 + i8) * 512 + k0 + cl, &As[R0][0]);
        }
        #pragma unroll
        for (int g = 0; g < 4; ++g) {
            const int R0 = (wave * 4 + g) * 8;
            glds16(Bk + (long)(R0 + i8) * 512 + k0 + cl, &Bs[R0][0]);
        }
        __syncthreads();

        #pragma unroll
        for (int ksub = 0; ksub < 2; ++ksub) {
            f16x8 af[4], bf[4];
            #pragma unroll
            for (int i = 0; i < 4; ++i) {
                const int r  = wr * 64 + i * 16 + l16;
                const int pc = ((ksub * 32 + quad * 8) + ((r & 7) * 8)) & 63;
                af[i] = *(const f16x8*)&As[r][pc];
            }
            #pragma unroll
            for (int j = 0; j < 4; ++j) {
                const int r  = wc * 64 + j * 16 + l16;
                const int pc = ((ksub * 32 + quad * 8) + ((r & 7) * 8)) & 63;
                bf[j] = *(const f16x8*)&Bs[r][pc];
            }
            #pragma unroll
            for (int i = 0; i < 4; ++i)
                #pragma unroll
                for (int j = 0; j < 4; ++j)
                    acc[i][j] = __builtin_amdgcn_mfma_f32_16x16x32_f16(
                        af[i], bf[j], acc[i][j], 0, 0, 0);
        }
    }

    // ---- softmax (rows of 256) ----
    const float scale = 0.044194173824159216f;  // 1/sqrt(512)
    float st[4][4];
    #pragma unroll
    for (int i = 0; i < 4; ++i)
        #pragma unroll
        for (int r = 0; r < 4; ++r) {
            float m = acc[i][0][r];
            #pragma unroll
            for (int j = 1; j < 4; ++j) m = fmaxf(m, acc[i][j][r]);
            st[i][r] = m;
        }
    #pragma unroll
    for (int off = 1; off < 16; off <<= 1)
        #pragma unroll
        for (int i = 0; i < 4; ++i)
            #pragma unroll
            for (int r = 0; r < 4; ++r)
                st[i][r] = fmaxf(st[i][r], __shfl_xor(st[i][r], off, 64));
    if (l16 == 0)
        #pragma unroll
        for (int i = 0; i < 4; ++i)
            #pragma unroll
            for (int r = 0; r < 4; ++r)
                red[0][wr * 64 + i * 16 + quad * 4 + r][wc] = st[i][r];
    __syncthreads();   // also: last As/Bs reads done -> bufA reusable as Ps

    // exp (unnormalized, e<=1) -> Ps (swizzled); local sums
    #pragma unroll
    for (int i = 0; i < 4; ++i)
        #pragma unroll
        for (int r = 0; r < 4; ++r) {
            const int row = wr * 64 + i * 16 + quad * 4 + r;
            const float m = fmaxf(fmaxf(red[0][row][0], red[0][row][1]),
                                  fmaxf(red[0][row][2], red[0][row][3]));
            float s = 0.f;
            #pragma unroll
            for (int j = 0; j < 4; ++j) {
                const float e = __expf(scale * (acc[i][j][r] - m));
                s += e;
                const int col = wc * 64 + j * 16 + l16;
                // per-64-col group rotation swizzle (granule = 8 f16)
                Ps[row][(col & 192) + (((col & 63) + ((row & 7) * 8)) & 63)] = (f16)e;
            }
            st[i][r] = s;
        }
    #pragma unroll
    for (int off = 1; off < 16; off <<= 1)
        #pragma unroll
        for (int i = 0; i < 4; ++i)
            #pragma unroll
            for (int r = 0; r < 4; ++r)
                st[i][r] += __shfl_xor(st[i][r], off, 64);
    if (l16 == 0)
        #pragma unroll
        for (int i = 0; i < 4; ++i)
            #pragma unroll
            for (int r = 0; r < 4; ++r)
                red[1][wr * 64 + i * 16 + quad * 4 + r][wc] = st[i][r];
    __syncthreads();

    if (tid < 128) {
        const float s = red[1][tid][0] + red[1][tid][1] +
                        red[1][tid][2] + red[1][tid][3];
        red[0][tid][0] = 1.0f / s;   // per-row inverse sum for deferred norm
    }

    // ---- stage 2: O = P V  (M=128, N=512, K=256; P entirely in LDS) ----
    // wave layout 2x4 over a 128x128 n-chunk: wave = 64 rows x 32 cols.
    for (int nc = 0; nc < 4; ++nc) {
        const int n0c = nc * 128;
        __syncthreads();   // Vs reuse guard; nc=0: publishes Ps + inv
        #pragma unroll
        for (int kb = 0; kb < 4; ++kb)
            #pragma unroll
            for (int g = 0; g < 2; ++g) {
                const int R0 = (wave * 2 + g) * 8;
                glds16(Vt + (long)(n0c + R0 + i8) * 256 + kb * 64 + cl,
                       &Vs[kb][R0][0]);
            }
        __syncthreads();

        f32x4 acc2[4][2];
        #pragma unroll
        for (int i = 0; i < 4; ++i)
            #pragma unroll
            for (int j = 0; j < 2; ++j)
                acc2[i][j] = (f32x4){0.f, 0.f, 0.f, 0.f};

        #pragma unroll
        for (int kb = 0; kb < 4; ++kb)
            #pragma unroll
            for (int ksub = 0; ksub < 2; ++ksub) {
                f16x8 af[4], bf[2];
                #pragma unroll
                for (int i = 0; i < 4; ++i) {
                    const int r  = wr * 64 + i * 16 + l16;
                    const int pc = kb * 64 +
                        (((ksub * 32 + quad * 8) + ((r & 7) * 8)) & 63);
                    af[i] = *(const f16x8*)&Ps[r][pc];
                }
                #pragma unroll
                for (int j = 0; j < 2; ++j) {
                    const int rv = wc * 32 + j * 16 + l16;
                    const int pc = ((ksub * 32 + quad * 8) + ((rv & 7) * 8)) & 63;
                    bf[j] = *(const f16x8*)&Vs[kb][rv][pc];
                }
                #pragma unroll
                for (int i = 0; i < 4; ++i)
                    #pragma unroll
                    for (int j = 0; j < 2; ++j)
                        acc2[i][j] = __builtin_amdgcn_mfma_f32_16x16x32_f16(
                            af[i], bf[j], acc2[i][j], 0, 0, 0);
            }

        #pragma unroll
        for (int i = 0; i < 4; ++i)
            #pragma unroll
            for (int j = 0; j < 2; ++j) {
                const int col = n0c + wc * 32 + j * 16 + l16;
                #pragma unroll
                for (int rr = 0; rr < 4; ++rr) {
                    const int row = wr * 64 + i * 16 + quad * 4 + rr;
                    const float inv = red[0][row][0];
                    O[(long)z * 131072 + (long)(m0 + row) * 512 + col] =
                        (f16)(acc2[i][j][rr] * inv);
                }
            }
    }
}

__global__ __launch_bounds__(256)
void cvt3(const float* __restrict__ a, const float* __restrict__ b,
          const float* __restrict__ c, f16* __restrict__ oa,
          f16* __restrict__ ob, f16* __restrict__ oc)
{
    const int w = blockIdx.x >> 8;
    const int t = ((blockIdx.x & 255) * 256 + threadIdx.x) * 4;
    const float* src = (w == 0) ? a : (w == 1) ? b : c;
    f16* dst = (w == 0) ? oa : (w == 1) ? ob : oc;
    const float4 v = *(const float4*)(src + t);
    f16x4 o;
    o[0] = (f16)v.x; o[1] = (f16)v.y; o[2] = (f16)v.z; o[3] = (f16)v.w;
    *(f16x4*)(dst + t) = o;
}

extern "C" void kernel_launch(void* const* d_in, const int* in_sizes, int n_in,
                              void* d_out, int out_size, void* d_ws, size_t ws_size,
                              hipStream_t stream)
{
    const float* queries = (const float*)d_in[0];
    const float* keys    = (const float*)d_in[1];
    const float* values  = (const float*)d_in[2];
    const float* Wq      = (const float*)d_in[3];
    const float* bq      = (const float*)d_in[4];
    const float* Wkv     = (const float*)d_in[5];
    const float* bkv     = (const float*)d_in[6];
    const float* Wo      = (const float*)d_in[7];
    const float* bo      = (const float*)d_in[8];
    float* out = (float*)d_out;

    // f16 workspace layout (~102 MB):
    f16* ws  = (f16*)d_ws;
    f16* wq  = ws;                      //   262144
    f16* wkv = ws + 262144;
    f16* wo  = ws + 524288;
    f16* qh  = ws + 786432;             // 32 MB  q  (ao overlays after fused attn)
    f16* kh  = qh + 16777216;           // 32 MB  k
    f16* vT  = kh + 16777216;           // 32 MB  v^T
    f16* ao  = qh;                      // overlay: fused kernel writes the exact
                                        // qh rows only it reads, after last read

    cvt3<<<768, 256, 0, stream>>>(Wq, Wkv, Wo, wq, wkv, wo);

    proj3<<<3072, dim3(256), 0, stream>>>(
        queries, keys, values, wq, wkv, bq, bkv, qh, kh, vT);

    attn_fused<<<256, 512, 0, stream>>>(qh, kh, vT, ao);

    gemm_nt<false, true, false, true, 1><<<1024, dim3(256), 0, stream>>>(
        ao, wo, bo, out, 512, 512, 0, 0, 0);
}